// Round 1
// 391.302 us; speedup vs baseline: 1.0387x; 1.0387x over previous
//
#include <hip/hip_runtime.h>
#include <cstdint>
#include <cstddef>

#define NE 16
#define NB 32768
#define LATENT 128
#define HID 64
#define CLASSES 10
#define WPE 32               // blocks per expert
#define STRIP (NB / WPE)     // 1024 tokens scanned per block

// ---------------------------------------------------------------------------
// Single fused kernel, zero workspace use.
// Block (e, blk) scans mask[e] over its 1024-token strip, compacts matching
// token ids into an LDS list (~64 +/- 8 tokens expected), then runs the
// proven transposed-LDS MLP core on 64-token tiles.
//   - mask mode probe (byte-bool vs 4-byte word) kept from previous version:
//     byte offsets b=1+4t are nonzero for byte one-hot columns, always 0x00
//     for int32(1)/float32(1.0) words.
//   - compute core identical to the verified expert_kernel (same fp32
//     accumulation order), list read from LDS instead of global.
// Removes: memset dispatch, assign dispatch, global atomics, 64 KB lists
// round-trip, and all d_ws traffic.
// ---------------------------------------------------------------------------
__global__ __launch_bounds__(256) void fused_kernel(
    const void* __restrict__ mask,
    const float* __restrict__ latent,
    const float* __restrict__ W1, const float* __restrict__ b1,
    const float* __restrict__ W2, const float* __restrict__ b2,
    const float* __restrict__ W3, const float* __restrict__ b3,
    float* __restrict__ out)
{
    __shared__ float sX[LATENT * 64];          // [l][tok] transposed; reused h1,h2
    __shared__ unsigned short sList[STRIP];    // token ids matched in this strip
    __shared__ int sN;
    __shared__ int sMode;

    const int e    = blockIdx.x >> 5;          // expert
    const int blk  = blockIdx.x & 31;          // strip index within expert
    const int tid  = threadIdx.x;
    const int lane = tid & 63;
    const int jh   = __builtin_amdgcn_readfirstlane(tid >> 6);  // wave 0..3

    if (tid == 0) { sN = 0; sMode = 0; }
    __syncthreads();

    // ---- mask storage-mode probe (byte-bool vs word) ----
    if (tid < 32) {
        const unsigned char* mb = (const unsigned char*)mask;
        int b = 1 + 4 * tid;
        int nz = 0;
        #pragma unroll
        for (int ee = 0; ee < NE; ++ee) nz |= mb[(size_t)ee * NB + b];
        if (nz) atomicOr(&sMode, 1);
    }
    __syncthreads();

    // ---- scan this expert's strip, compact matches into sList ----
    const int tok0 = blk * STRIP;
    if (sMode) {
        const uchar4* m = (const uchar4*)((const unsigned char*)mask
                                          + (size_t)e * NB + tok0);
        uchar4 v = m[tid];
        unsigned char c[4] = {v.x, v.y, v.z, v.w};
        #pragma unroll
        for (int k = 0; k < 4; ++k)
            if (c[k]) {
                int p = atomicAdd(&sN, 1);
                sList[p] = (unsigned short)(tok0 + tid * 4 + k);
            }
    } else {
        const int4* m = (const int4*)((const int*)mask + (size_t)e * NB + tok0);
        int4 v = m[tid];   // also correct for float32 0.0/1.0 bit patterns
        int c[4] = {v.x, v.y, v.z, v.w};
        #pragma unroll
        for (int k = 0; k < 4; ++k)
            if (c[k] != 0) {
                int p = atomicAdd(&sN, 1);
                sList[p] = (unsigned short)(tok0 + tid * 4 + k);
            }
    }
    __syncthreads();

    const int cnt = sN;
    if (cnt == 0) return;                      // uniform per block — safe
    const int ntiles = (cnt + 63) >> 6;

    const float* w1e = W1 + (size_t)e * LATENT * HID + jh * 16;
    const float* w2e = W2 + (size_t)e * HID * HID + jh * 16;
    const float* b1e = b1 + e * HID + jh * 16;
    const float* b2e = b2 + e * HID + jh * 16;
    const float* w3e = W3 + (size_t)e * HID * CLASSES + jh * 5;   // waves 0,1
    const float* b3e = b3 + e * CLASSES + jh * 5;

    for (int tile = 0; tile < ntiles; ++tile) {
        const int base = tile * 64;

        // ---- stage 64 token rows into sX[l][tok] (transposed) ----
        {
            const int s = lane, q = jh;        // token slot, quarter-row index
            int idx = base + s;
            if (idx >= cnt) idx = cnt - 1;     // duplicate tail row, store guarded
            const int tok = sList[idx];
            const float4* src = (const float4*)
                (latent + ((size_t)e * NB + tok) * LATENT + q * 32);
            #pragma unroll
            for (int i = 0; i < 8; ++i) {
                float4 v = src[i];
                int l = q * 32 + i * 4;
                sX[(l + 0) * 64 + s] = v.x;
                sX[(l + 1) * 64 + s] = v.y;
                sX[(l + 2) * 64 + s] = v.z;
                sX[(l + 3) * 64 + s] = v.w;
            }
        }
        __syncthreads();

        // ---- layer 1: 128 -> 64 (this wave: 16 channels), relu ----
        float acc[16];
        #pragma unroll
        for (int j = 0; j < 16; ++j) acc[j] = b1e[j];
        #pragma unroll 4
        for (int l = 0; l < LATENT; ++l) {
            float x = sX[l * 64 + lane];
            const float* wr = w1e + l * HID;
            #pragma unroll
            for (int j = 0; j < 16; ++j) acc[j] = fmaf(x, wr[j], acc[j]);
        }
        __syncthreads();                       // all reads of sX done
        #pragma unroll
        for (int j = 0; j < 16; ++j)
            sX[(jh * 16 + j) * 64 + lane] = fmaxf(acc[j], 0.f);
        __syncthreads();

        // ---- layer 2: 64 -> 64 (this wave: 16 channels), relu ----
        float acc2[16];
        #pragma unroll
        for (int j = 0; j < 16; ++j) acc2[j] = b2e[j];
        #pragma unroll 4
        for (int l = 0; l < HID; ++l) {
            float x = sX[l * 64 + lane];
            const float* wr = w2e + l * HID;
            #pragma unroll
            for (int j = 0; j < 16; ++j) acc2[j] = fmaf(x, wr[j], acc2[j]);
        }
        __syncthreads();                       // all reads of h1 done
        #pragma unroll
        for (int j = 0; j < 16; ++j)
            sX[(jh * 16 + j) * 64 + lane] = fmaxf(acc2[j], 0.f);
        __syncthreads();

        // ---- layer 3: 64 -> 10; waves 0,1 take 5 classes each ----
        if (jh < 2) {
            float a3[5];
            #pragma unroll
            for (int c = 0; c < 5; ++c) a3[c] = b3e[c];
            #pragma unroll 4
            for (int l = 0; l < HID; ++l) {
                float x = sX[l * 64 + lane];
                const float* wr = w3e + l * CLASSES;
                #pragma unroll
                for (int c = 0; c < 5; ++c) a3[c] = fmaf(x, wr[c], a3[c]);
            }
            int slot = base + lane;
            if (slot < cnt) {
                int tok = sList[slot];
                float* o = out + (size_t)tok * CLASSES + jh * 5;
                #pragma unroll
                for (int c = 0; c < 5; ++c) o[c] = a3[c];
            }
        }
        __syncthreads();                       // protect sX before next staging
    }
}

extern "C" void kernel_launch(void* const* d_in, const int* in_sizes, int n_in,
                              void* d_out, int out_size, void* d_ws, size_t ws_size,
                              hipStream_t stream) {
    // inputs: 0=x(unused), 1=mask, 2=latent, 3=W1, 4=b1, 5=W2, 6=b2, 7=W3, 8=b3
    const void*  mask   = d_in[1];
    const float* latent = (const float*)d_in[2];
    const float* W1 = (const float*)d_in[3];
    const float* b1 = (const float*)d_in[4];
    const float* W2 = (const float*)d_in[5];
    const float* b2 = (const float*)d_in[6];
    const float* W3 = (const float*)d_in[7];
    const float* b3 = (const float*)d_in[8];
    float* out = (float*)d_out;

    (void)d_ws; (void)ws_size;   // workspace intentionally untouched

    fused_kernel<<<NE * WPE, 256, 0, stream>>>(mask, latent,
                                               W1, b1, W2, b2, W3, b3, out);
}